// Round 1
// baseline (9004.979 us; speedup 1.0000x reference)
//
#include <hip/hip_runtime.h>
#include <math.h>

#define T_STEPS 1024
#define NB 64        // batch
#define NH 512       // hidden
#define NI 256       // input
#define GSIZE 8      // WGs per batch-group (hidden slices)
#define NGRP 8       // batch groups
#define BPG 8        // batches per group
#define HPW 64       // hidden columns per WG

// d_ws layout
#define WS_CNT_BYTES 4096
#define WS_YBUF_OFF  4096                      // double-buffered y: 2*64*512 f32
#define WS_INIT_BYTES (WS_YBUF_OFF + 2*NB*NH*4)

// ---------------------------------------------------------------------------
// Kernel 1: ext[t,b,h] = inputs[t,b,:] @ W_ih[:,h] + b_ih[h], written to d_out.
// Grid: 1024 blocks = 8 h-groups (64 h each) x 128 row-groups (512 rows each).
// W slice staged in LDS (exactly 64KB static); inputs streamed via L1.
// ---------------------------------------------------------------------------
__global__ __launch_bounds__(256) void ext_gemm_kernel(
    const float* __restrict__ inputs, const float* __restrict__ W_ih,
    const float* __restrict__ b_ih, float* __restrict__ out)
{
    __shared__ float Wt[NI * 64];   // [i][h], 64 KiB
    const int tid    = threadIdx.x;
    const int hgrp   = blockIdx.x & 7;
    const int rowgrp = blockIdx.x >> 3;
    const int hbase  = hgrp * 64;
    const long rowbase = (long)rowgrp * 512;

    for (int idx = tid; idx < NI * 64; idx += 256) {
        int i  = idx >> 6;
        int hh = idx & 63;
        Wt[idx] = W_ih[(size_t)i * NH + hbase + hh];
    }
    const int hq = tid & 15;   // h quad -> h = hq*4 .. hq*4+3
    const int r  = tid >> 4;   // row within 16-row chunk
    const float4 bias = *(const float4*)&b_ih[hbase + hq * 4];
    __syncthreads();

    for (int rc = 0; rc < 32; ++rc) {
        const long row = rowbase + rc * 16 + r;
        const float* __restrict__ inrow = inputs + row * NI;
        float ax = 0.f, ay = 0.f, az = 0.f, aw = 0.f;
        #pragma unroll 4
        for (int i = 0; i < NI; i += 4) {
            const float4 a  = *(const float4*)(inrow + i);
            const float4 w0 = *(const float4*)&Wt[(i + 0) * 64 + hq * 4];
            const float4 w1 = *(const float4*)&Wt[(i + 1) * 64 + hq * 4];
            const float4 w2 = *(const float4*)&Wt[(i + 2) * 64 + hq * 4];
            const float4 w3 = *(const float4*)&Wt[(i + 3) * 64 + hq * 4];
            ax += a.x * w0.x + a.y * w1.x + a.z * w2.x + a.w * w3.x;
            ay += a.x * w0.y + a.y * w1.y + a.z * w2.y + a.w * w3.y;
            az += a.x * w0.z + a.y * w1.z + a.z * w2.z + a.w * w3.z;
            aw += a.x * w0.w + a.y * w1.w + a.z * w2.w + a.w * w3.w;
        }
        float4 o = make_float4(ax + bias.x, ay + bias.y, az + bias.z, aw + bias.w);
        *(float4*)&out[row * NH + hbase + hq * 4] = o;
    }
}

// ---------------------------------------------------------------------------
// Kernel 2: persistent recurrent scan. 64 WGs x 512 threads.
//   blockIdx: grp = bid & 7 (batch group -> same XCD under round-robin),
//             hgrp = bid >> 3 (hidden slice).
// Each WG: W_hh[:, hbase:hbase+64] in registers (k-split 8), batches
// bbase..bbase+7. Per step: stage group's y (8x512) from global into LDS,
// GEMM (wave-uniform broadcast reads), k-group reduce via LDS, elementwise
// update, write x_t over ext slot in d_out, write y_t to the other y buffer,
// 8-WG group barrier (monotonic counter, release/acquire agent scope).
// ---------------------------------------------------------------------------
__global__ __launch_bounds__(512) void horn_recurrent_kernel(
    const float* __restrict__ W_hh, const float* __restrict__ b_hh,
    const float* __restrict__ alpha, const float* __restrict__ omega,
    const float* __restrict__ gamma, const float* __restrict__ v,
    float* __restrict__ out, float* __restrict__ ybuf,
    unsigned* __restrict__ counters)
{
    __shared__ float y_lds[BPG * NH];            // 16 KiB
    __shared__ float part[GSIZE][BPG][HPW];      // 16 KiB

    const int tid   = threadIdx.x;
    const int grp   = blockIdx.x & 7;    // batch group (XCD-local under round-robin)
    const int hgrp  = blockIdx.x >> 3;   // hidden slice
    const int bbase = grp * BPG;
    const int hbase = hgrp * HPW;

    // GEMM mapping
    const int kgrp = tid >> 6;   // 0..7 (k-split)
    const int hk   = tid & 63;   // h within slice
    // update mapping (numerically identical split, different roles)
    const int b2 = tid >> 6;     // 0..7
    const int h2 = tid & 63;
    const int hg = hbase + h2;   // global h

    // per-thread W_hh slice: W_hh[kgrp*64 + kk][hbase + hk], kk = 0..63
    float wreg[64];
    {
        const float* wp = W_hh + (size_t)(kgrp * 64) * NH + hbase + hk;
        #pragma unroll
        for (int kk = 0; kk < 64; ++kk) wreg[kk] = wp[(size_t)kk * NH];
    }
    const float bhh_r = b_hh[hg];
    const float al_r  = alpha[hg];
    const float omv   = omega[hg];
    const float om2_r = omv * omv;
    const float g2_r  = 2.0f * gamma[hg];
    const float v_r   = v[hg];
    const float gain  = 0.04419417382415922f;   // 1/sqrt(512)
    const float hdt   = 0.1f;

    unsigned* cnt = counters + grp * 64;   // 256B spacing per group

    float x = 0.f, y = 0.f;

    for (int t = 0; t < T_STEPS; ++t) {
        // stage previous y (this group's 8 rows) global -> LDS, coalesced
        {
            const float* src = ybuf + (size_t)(t & 1) * NB * NH + (size_t)bbase * NH;
            const int fo = tid * 8;
            float4 a0 = *(const float4*)(src + fo);
            float4 a1 = *(const float4*)(src + fo + 4);
            float* yl = y_lds;
            *(float4*)(yl + fo)     = a0;
            *(float4*)(yl + fo + 4) = a1;
        }
        // prefetch external input for this (b,h); consumed after GEMM
        const size_t eidx = ((size_t)t * NB + bbase + b2) * NH + hg;
        const float e = out[eidx];
        __syncthreads();

        // GEMM: acc[b] = sum over this thread's 64 k of y[b][k]*W[k][h]
        float acc[8];
        #pragma unroll
        for (int b = 0; b < 8; ++b) acc[b] = 0.f;
        {
            const int kb = kgrp * 64;
            #pragma unroll
            for (int q = 0; q < 16; ++q) {
                const float w0 = wreg[q * 4 + 0], w1 = wreg[q * 4 + 1];
                const float w2 = wreg[q * 4 + 2], w3 = wreg[q * 4 + 3];
                #pragma unroll
                for (int b = 0; b < 8; ++b) {
                    const float4 yv = *(const float4*)&y_lds[b * NH + kb + q * 4];
                    acc[b] += yv.x * w0 + yv.y * w1 + yv.z * w2 + yv.w * w3;
                }
            }
        }
        #pragma unroll
        for (int b = 0; b < 8; ++b) part[kgrp][b][hk] = acc[b];
        __syncthreads();

        // reduce over k-groups + bias
        float rec = bhh_r;
        #pragma unroll
        for (int g = 0; g < GSIZE; ++g) rec += part[g][b2][h2];

        // elementwise update (matches reference order of operations)
        const float inp  = e + gain * (rec + v_r * x);
        const float ynew = y + hdt * (al_r * tanhf(inp) - om2_r * x - g2_r * y);
        const float xnew = x + hdt * ynew;
        out[eidx] = xnew;
        ybuf[(size_t)((t + 1) & 1) * NB * NH + (size_t)(bbase + b2) * NH + hg] = ynew;
        x = xnew; y = ynew;

        if (t == T_STEPS - 1) break;

        // group barrier: all 8 WGs of this batch group
        __threadfence_block();           // drain this wave's stores toward L2
        __syncthreads();                 // all waves drained
        if (tid == 0) {
            __threadfence();             // agent fence: L2 writeback (cross-XCD safe)
            __hip_atomic_fetch_add(cnt, 1u, __ATOMIC_RELEASE, __HIP_MEMORY_SCOPE_AGENT);
            const unsigned target = (unsigned)GSIZE * (unsigned)(t + 1);
            while (__hip_atomic_load(cnt, __ATOMIC_ACQUIRE, __HIP_MEMORY_SCOPE_AGENT) < target) { }
        }
        __syncthreads();                 // release WG after thread-0 acquire
    }
}

// ---------------------------------------------------------------------------
extern "C" void kernel_launch(void* const* d_in, const int* in_sizes, int n_in,
                              void* d_out, int out_size, void* d_ws, size_t ws_size,
                              hipStream_t stream) {
    const float* inputs = (const float*)d_in[0];
    const float* W_ih   = (const float*)d_in[1];
    const float* b_ih   = (const float*)d_in[2];
    const float* W_hh   = (const float*)d_in[3];
    const float* b_hh   = (const float*)d_in[4];
    const float* alpha  = (const float*)d_in[5];
    const float* omega  = (const float*)d_in[6];
    const float* gamma  = (const float*)d_in[7];
    const float* v      = (const float*)d_in[8];
    float* out = (float*)d_out;

    unsigned* counters = (unsigned*)d_ws;
    float* ybuf = (float*)((char*)d_ws + WS_YBUF_OFF);

    // zero barrier counters + y state (d_ws is re-poisoned before every launch)
    hipMemsetAsync(d_ws, 0, WS_INIT_BYTES, stream);

    // ext = inputs @ W_ih + b_ih, written into d_out (overwritten step-by-step)
    ext_gemm_kernel<<<dim3(1024), dim3(256), 0, stream>>>(inputs, W_ih, b_ih, out);

    // sequential scan, persistent kernel
    horn_recurrent_kernel<<<dim3(64), dim3(512), 0, stream>>>(
        W_hh, b_hh, alpha, omega, gamma, v, out, ybuf, counters);
}